// Round 2
// baseline (566.253 us; speedup 1.0000x reference)
//
#include <hip/hip_runtime.h>
#include <hip/hip_bf16.h>
#include <cstdint>

#define B_   2
#define T_   4096
#define D_   1024
#define H_   16
#define DH_  64
#define M_   (B_*T_)     // 8192 rows
#define K3_  (3*D_)      // 3072
#define TC_  128         // cumsum chunk
#define NCH_ (T_/TC_)    // 32 chunks

typedef __attribute__((ext_vector_type(4))) float  f32x4;
typedef __attribute__((ext_vector_type(8))) short  short8;

__device__ __forceinline__ float bf2f(ushort u) {
    union { uint32_t i; float f; } v; v.i = ((uint32_t)u) << 16; return v.f;
}
__device__ __forceinline__ ushort f2bf(float f) {
    union { float f; uint32_t i; } v; v.f = f;
    uint32_t r = v.i + 0x7FFF + ((v.i >> 16) & 1);
    return (ushort)(r >> 16);
}

template<bool F32>
__device__ __forceinline__ float ld_in(const void* p, size_t i) {
    if (F32) return ((const float*)p)[i];
    return bf2f(((const ushort*)p)[i]);
}

// store helpers: bf16 internal buffers vs f32 final output
__device__ __forceinline__ void st_c(ushort* p, float v) { *p = f2bf(v); }
__device__ __forceinline__ void st_c(float*  p, float v) { *p = v; }

#define GLOAD_LDS16(g, l) \
    __builtin_amdgcn_global_load_lds((const __attribute__((address_space(1))) void*)(g), \
                                     (__attribute__((address_space(3))) void*)(l), 16, 0, 0)

// ---------------- P0: dtype detector ----------------
__global__ void detect_kernel(const ushort* __restrict__ xu, int* __restrict__ flag) {
    __shared__ int cnt;
    if (threadIdx.x == 0) cnt = 0;
    __syncthreads();
    int c = 0;
    for (int i = threadIdx.x; i < 16384; i += 256) {
        ushort u = xu[i];
        if ((u & 0x7F80) == 0x7F80) c++;
    }
    if (c) atomicAdd(&cnt, c);
    __syncthreads();
    if (threadIdx.x == 0) flag[0] = (cnt > 0) ? 1 : 0;
}

// ---------------- P1: gates -> telescoping chain ratios ----------------
// g9[row][p*3+s] stores: s=0: g0/g1', s=1: g1'/g2', s=2: g2'  (g'=max(g,1e-30))
// GEMM multiplies acc by ratio after each K-segment -> net coeffs g0,g1',g2'
// with a SINGLE accumulator.
template<bool F32>
__device__ __forceinline__ void gates_body(const void* x,
                                           const void* Wg_q, const void* bg_q,
                                           const void* Wg_k, const void* bg_k,
                                           const void* Wg_v, const void* bg_v,
                                           float* __restrict__ g9) {
    const int wave = threadIdx.x >> 6, lane = threadIdx.x & 63;
    const int row  = blockIdx.x * 4 + wave;
    const size_t xoff = (size_t)row * D_;
    float acc[9] = {0,0,0,0,0,0,0,0,0};
    for (int d = lane; d < D_; d += 64) {
        float xv = ld_in<F32>(x, xoff + d);
        #pragma unroll
        for (int c = 0; c < 3; c++) {
            acc[0+c] += xv * ld_in<F32>(Wg_q, d*3+c);
            acc[3+c] += xv * ld_in<F32>(Wg_k, d*3+c);
            acc[6+c] += xv * ld_in<F32>(Wg_v, d*3+c);
        }
    }
    #pragma unroll
    for (int i = 0; i < 9; i++) {
        #pragma unroll
        for (int o = 32; o >= 1; o >>= 1) acc[i] += __shfl_xor(acc[i], o, 64);
    }
    const void* bgs[3] = {bg_q, bg_k, bg_v};
    float g[9];
    #pragma unroll
    for (int p = 0; p < 3; p++) {
        float l0 = acc[p*3+0] + ld_in<F32>(bgs[p], 0);
        float l1 = acc[p*3+1] + ld_in<F32>(bgs[p], 1);
        float l2 = acc[p*3+2] + ld_in<F32>(bgs[p], 2);
        float mx = fmaxf(l0, fmaxf(l1, l2));
        float e0 = expf(l0-mx), e1 = expf(l1-mx), e2 = expf(l2-mx);
        float s  = e0+e1+e2;
        float g0 = fminf(e0/s, 0.6f), g1 = fminf(e1/s, 0.6f), g2 = fminf(e2/s, 0.6f);
        float s2 = g0+g1+g2;
        g0 /= s2; g1 /= s2; g2 /= s2;
        float g1c = fmaxf(g1, 1e-30f), g2c = fmaxf(g2, 1e-30f);
        g[p*3+0] = g0 / g1c;
        g[p*3+1] = g1c / g2c;
        g[p*3+2] = g2c;
    }
    if (lane == 0) {
        #pragma unroll
        for (int i = 0; i < 9; i++) g9[(size_t)row*9 + i] = g[i];
    }
}
__global__ void gates_kernel(const void* x,
                             const void* Wg_q, const void* bg_q,
                             const void* Wg_k, const void* bg_k,
                             const void* Wg_v, const void* bg_v,
                             const int* __restrict__ flag, float* __restrict__ g9) {
    if (flag[0]) gates_body<true >(x, Wg_q, bg_q, Wg_k, bg_k, Wg_v, bg_v, g9);
    else         gates_body<false>(x, Wg_q, bg_q, Wg_k, bg_k, Wg_v, bg_v, g9);
}

// ---------------- P2: per-chunk sums ----------------
template<bool F32>
__device__ __forceinline__ void chunk_sum_body(const void* x, float* __restrict__ part) {
    const int d = blockIdx.x * 256 + threadIdx.x;
    const int tc = blockIdx.y, b = blockIdx.z;
    const size_t base = ((size_t)b*T_ + (size_t)tc*TC_) * D_ + d;
    float s = 0.f;
    for (int i = 0; i < TC_; i++) s += ld_in<F32>(x, base + (size_t)i * D_);
    part[((size_t)b*NCH_ + tc) * D_ + d] = s;
}
__global__ void chunk_sum_kernel(const void* x, const int* __restrict__ flag,
                                 float* __restrict__ part) {
    if (flag[0]) chunk_sum_body<true >(x, part);
    else         chunk_sum_body<false>(x, part);
}

// ---------------- P3: exclusive scan of chunk sums ----------------
__global__ void scan_part_kernel(float* __restrict__ part) {
    const int idx = blockIdx.x * 256 + threadIdx.x;   // 0..2047
    const int b = idx >> 10, d = idx & (D_-1);
    float run = 0.f;
    for (int tc = 0; tc < NCH_; tc++) {
        size_t o = ((size_t)b*NCH_ + tc) * D_ + d;
        float v = part[o]; part[o] = run; run += v;
    }
}

// ---------------- P4: build UNSCALED concat input Xc[row] = [x | integ | deriv] ----------------
template<bool F32>
__device__ __forceinline__ void build_xs_body(const void* x, const float* __restrict__ part,
                                              ushort* __restrict__ Xc) {
    const int d0 = (blockIdx.x * 256 + threadIdx.x) * 2;
    const int tc = blockIdx.y, b = blockIdx.z;
    const int t0 = tc * TC_;
    float carry0 = part[((size_t)b*NCH_ + tc) * D_ + d0];
    float carry1 = part[((size_t)b*NCH_ + tc) * D_ + d0 + 1];
    const size_t xbase = ((size_t)b*T_ + t0) * D_ + d0;
    float prev0 = (t0 > 0) ? ld_in<F32>(x, xbase - D_)     : 0.0f;
    float prev1 = (t0 > 0) ? ld_in<F32>(x, xbase - D_ + 1) : 0.0f;
    for (int i = 0; i < TC_; i++) {
        const int t = t0 + i;
        float xv0 = ld_in<F32>(x, xbase + (size_t)i * D_);
        float xv1 = ld_in<F32>(x, xbase + (size_t)i * D_ + 1);
        carry0 += xv0; carry1 += xv1;
        const float rinv = 1.0f / (float)(t + 1);
        float in0 = carry0 * rinv, in1 = carry1 * rinv;
        float de0 = (t == 0) ? 0.0f : (xv0 - prev0);
        float de1 = (t == 0) ? 0.0f : (xv1 - prev1);
        prev0 = xv0; prev1 = xv1;
        const size_t base = ((size_t)b*T_ + t) * K3_ + d0;
        *(ushort2*)(Xc + base       ) = make_ushort2(f2bf(xv0), f2bf(xv1));
        *(ushort2*)(Xc + base +   D_) = make_ushort2(f2bf(in0), f2bf(in1));
        *(ushort2*)(Xc + base + 2*D_) = make_ushort2(f2bf(de0), f2bf(de1));
    }
}
__global__ void build_xs_kernel(const void* x, const float* __restrict__ part,
                                const int* __restrict__ flag, ushort* __restrict__ Xc) {
    if (flag[0]) build_xs_body<true >(x, part, Xc);
    else         build_xs_body<false>(x, part, Xc);
}

// ---------------- P5: weight transpose -> (N,K) bf16 ----------------
struct WPtrs { const void* w[10]; };
template<bool F32>
__device__ __forceinline__ void transpose_w_body(WPtrs ptrs, ushort* __restrict__ Wt,
                                                 ushort* __restrict__ WoT) {
    const int z = blockIdx.z;                 // 0..8: W{p,j}; 9: Wo
    const void* src = ptrs.w[z];
    __shared__ float tile[32][33];
    const int tx = threadIdx.x & 31, ty = threadIdx.x >> 5;
    const int d0 = blockIdx.x * 32, c0 = blockIdx.y * 32;
    #pragma unroll
    for (int i = 0; i < 4; i++) {
        int r = ty + i*8;
        tile[r][tx] = ld_in<F32>(src, (size_t)(d0 + r) * D_ + c0 + tx);
    }
    __syncthreads();
    if (z < 9) {
        const int p = z / 3, j = z % 3;
        #pragma unroll
        for (int i = 0; i < 4; i++) {
            int r = ty + i*8;
            Wt[(size_t)(p*D_ + c0 + r) * K3_ + j*D_ + d0 + tx] = f2bf(tile[tx][r]);
        }
    } else {
        #pragma unroll
        for (int i = 0; i < 4; i++) {
            int r = ty + i*8;
            WoT[(size_t)(c0 + r) * D_ + d0 + tx] = f2bf(tile[tx][r]);
        }
    }
}
__global__ void transpose_w_kernel(WPtrs ptrs, const int* __restrict__ flag,
                                   ushort* __restrict__ Wt, ushort* __restrict__ WoT) {
    if (flag[0]) transpose_w_body<true >(ptrs, Wt, WoT);
    else         transpose_w_body<false>(ptrs, Wt, WoT);
}

// ---------------- QKV GEMM: 256x384 tile, BK=32, ring-3 LDS, counted vmcnt ----
// C(8192x3072) = Xc(8192x3072) * Wt(3072x3072)^T, bf16 in/out, f32 acc, gated.
// 8 waves (2M x 4N) -> per-wave 128x96 (8x6 16x16-frags, acc=192 VGPR).
// LDS traffic: 299 B read + 107 B write per MFMA (vs 704 for 128x256 r1 kernel).
// BK=32 => row stride 64 B => 64-lane ds_read_b128 is a natural bijection over
// each aligned 1 KB block: NO swizzle needed, linear global_load_lds staging.
// Grid 32x8 = 256 blocks = exactly one device-wave (no tail).
//
// vmcnt ledger (5 loads per tile per thread: A=2, B=3):
//   prologue: stage tile0->buf0, tile1->buf1 (10 loads); vmcnt(5) => t0 landed.
//   tile t: P1 issues 3 loads of t+2 -> buf (t+2)%3 (freed at end of t-1),
//           P2 issues 2 more. End of t: newest 5 outstanding = t+2's, so
//           vmcnt(5) proves t+1 landed. Drain vmcnt(0) only at t == NKT-2.
// Gate fold every 32 tiles; p is per-16-col fragment (BN=384 crosses proj
// boundaries; 16-col frags never straddle a 1024 boundary).
__global__ __launch_bounds__(512, 2) void gemm_qkv_kernel(
        const ushort* __restrict__ Abase,
        const ushort* __restrict__ Bt,
        ushort* __restrict__ C,
        const float* __restrict__ g9) {
    constexpr int BUFE = 20480;          // ushorts per ring buffer (40960 B)
    constexpr int NKT  = K3_ / 32;       // 96
    __shared__ __align__(16) ushort LDS[3 * BUFE];   // 122880 B
    const int tid  = threadIdx.x;
    const int lane = tid & 63;
    const int wave = tid >> 6;
    const int wm   = wave >> 2;          // 0..1
    const int wn   = wave & 3;           // 0..3
    const int quad = lane >> 4, l16 = lane & 15;

    // XCD-chunked bijective swizzle: 256 blocks, cpx=32, mchunk=4
    const int wg  = (blockIdx.x % 8) * 32 + blockIdx.x / 8;
    const int rem = wg & 31;
    const int mt  = (wg >> 5) * 4 + (rem & 3);
    const int nt  = rem >> 2;
    const int m0  = mt * 256;
    const int n0  = nt * 384;

    // staging sources (linear, no swizzle): 5 x 16B granules per thread/tile
    const ushort* gsrc[5]; int loff[5];
    #pragma unroll
    for (int g = 0; g < 5; g++) {
        const int I = g*512 + tid;
        if (I < 1024) {                              // A: 256 rows x 32 k
            gsrc[g] = Abase + (size_t)(m0 + (I >> 2)) * K3_ + (I & 3) * 8;
            loff[g] = I * 8;
        } else {                                     // B: 384 rows x 32 k
            const int J = I - 1024;
            gsrc[g] = Bt + (size_t)(n0 + (J >> 2)) * K3_ + (J & 3) * 8;
            loff[g] = 8192 + J * 8;
        }
    }
    // ds_read element offsets (within a buffer)
    int ard[8], brd[6];
    #pragma unroll
    for (int i = 0; i < 8; i++) ard[i] = (wm*128 + i*16 + l16) * 32 + quad*8;
    #pragma unroll
    for (int j = 0; j < 6; j++) brd[j] = 8192 + (wn*96 + j*16 + l16) * 32 + quad*8;

    f32x4 acc[8][6] = {};

    // prologue: tile0 -> buf0, tile1 -> buf1
    #pragma unroll
    for (int g = 0; g < 5; g++) GLOAD_LDS16(gsrc[g], &LDS[loff[g]]);
    #pragma unroll
    for (int g = 0; g < 5; g++) GLOAD_LDS16(gsrc[g] + 32, &LDS[BUFE + loff[g]]);
    asm volatile("s_waitcnt vmcnt(5)" ::: "memory");
    __builtin_amdgcn_s_barrier();

    for (int t = 0; t < NKT; ++t) {
        const int bs = (t % 3) * BUFE;
        const bool do_stage = (t + 2 < NKT);
        const int sb = ((t + 2) % 3) * BUFE;
        const int sk = (t + 2) * 32;

        short8 af[4], bfr[6], af2[4];

        // ---- phase 1: rows i0-3, all j ----
        #pragma unroll
        for (int i = 0; i < 4; i++) af[i]  = *(const short8*)&LDS[bs + ard[i]];
        #pragma unroll
        for (int j = 0; j < 6; j++) bfr[j] = *(const short8*)&LDS[bs + brd[j]];
        if (do_stage) {
            GLOAD_LDS16(gsrc[0] + sk, &LDS[sb + loff[0]]);
            GLOAD_LDS16(gsrc[1] + sk, &LDS[sb + loff[1]]);
            GLOAD_LDS16(gsrc[2] + sk, &LDS[sb + loff[2]]);
        }
        __builtin_amdgcn_s_barrier();
        asm volatile("s_waitcnt lgkmcnt(0)" ::: "memory");
        __builtin_amdgcn_sched_barrier(0);
        __builtin_amdgcn_s_setprio(1);
        #pragma unroll
        for (int i = 0; i < 4; i++)
            #pragma unroll
            for (int j = 0; j < 6; j++)
                acc[i][j] = __builtin_amdgcn_mfma_f32_16x16x32_bf16(af[i], bfr[j], acc[i][j], 0, 0, 0);
        __builtin_amdgcn_s_setprio(0);
        __builtin_amdgcn_s_barrier();

        // ---- phase 2: rows i4-7, all j (bfr reused in regs) ----
        #pragma unroll
        for (int i = 0; i < 4; i++) af2[i] = *(const short8*)&LDS[bs + ard[i+4]];
        if (do_stage) {
            GLOAD_LDS16(gsrc[3] + sk, &LDS[sb + loff[3]]);
            GLOAD_LDS16(gsrc[4] + sk, &LDS[sb + loff[4]]);
        }
        __builtin_amdgcn_s_barrier();
        asm volatile("s_waitcnt lgkmcnt(0)" ::: "memory");
        __builtin_amdgcn_sched_barrier(0);
        __builtin_amdgcn_s_setprio(1);
        #pragma unroll
        for (int i = 0; i < 4; i++)
            #pragma unroll
            for (int j = 0; j < 6; j++)
                acc[i+4][j] = __builtin_amdgcn_mfma_f32_16x16x32_bf16(af2[i], bfr[j], acc[i+4][j], 0, 0, 0);
        __builtin_amdgcn_s_setprio(0);
        if (do_stage)          asm volatile("s_waitcnt vmcnt(5)" ::: "memory");
        else if (t + 1 < NKT)  asm volatile("s_waitcnt vmcnt(0)" ::: "memory");
        __builtin_amdgcn_s_barrier();

        if ((t & 31) == 31) {
            // telescoping gate fold; p per 16-col fragment (never straddles 1024)
            const int seg = t >> 5;
            #pragma unroll
            for (int i = 0; i < 8; i++) {
                #pragma unroll
                for (int rg = 0; rg < 4; rg++) {
                    const int rrow = m0 + wm*128 + i*16 + quad*4 + rg;
                    const float* gr = &g9[(size_t)rrow * 9 + seg];
                    #pragma unroll
                    for (int j = 0; j < 6; j++) {
                        const int pj = (n0 + wn*96 + j*16) >> 10;
                        acc[i][j][rg] *= gr[pj*3];
                    }
                }
            }
        }
    }

    // epilogue: C/D layout col=lane&15, row=quad*4+reg  [m89/m91 verified]
    #pragma unroll
    for (int i = 0; i < 8; i++) {
        #pragma unroll
        for (int j = 0; j < 6; j++) {
            const int rrow = m0 + wm*128 + i*16 + quad*4;
            const int col  = n0 + wn*96 + j*16 + l16;
            #pragma unroll
            for (int rg = 0; rg < 4; rg++)
                C[(size_t)(rrow + rg) * K3_ + col] = f2bf(acc[i][j][rg]);
        }
    }
}

// ---------------- out-proj GEMM (round-1 kernel, proven): 128x256 tile ------
template<typename CT, int NTILES, bool GATED>
__global__ __launch_bounds__(512, 2) void gemm_bt8_kernel(
        const ushort* __restrict__ Abase,
        const ushort* __restrict__ Bt,
        CT* __restrict__ C,
        const float* __restrict__ g9,
        int K, int lda, int ldc) {
    __shared__ __align__(16) ushort LDS[3 * 24576];
    const int tid  = threadIdx.x;
    const int lane = tid & 63;
    const int wave = tid >> 6;
    const int wm   = wave >> 2;
    const int wn   = wave & 3;
    const int quad = lane >> 4, l16 = lane & 15, sw = l16 & 7;

    const int MT     = M_ / 128;                 // 64
    const int cpx    = (MT * NTILES) / 8;
    const int wg     = (blockIdx.x % 8) * cpx + blockIdx.x / 8;
    const int mchunk = MT / 8;                   // 8
    const int rem    = wg % (mchunk * NTILES);
    const int mt     = (wg / (mchunk * NTILES)) * mchunk + (rem % mchunk);
    const int nt     = rem / mchunk;
    const int m0 = mt * 128;
    const int n0 = nt * 256;
    const int p  = n0 >> 10;

    const ushort* asrc[2]; int aoff[2];
    #pragma unroll
    for (int g = 0; g < 2; g++) {
        const int I = g*512 + tid;
        const int row = I >> 3, c8 = (I & 7) ^ (row & 7);
        asrc[g] = Abase + (size_t)(m0 + row) * lda + c8*8;
        aoff[g] = I * 8;
    }
    const ushort* bsrc[4]; int boff[4];
    #pragma unroll
    for (int g = 0; g < 4; g++) {
        const int I = g*512 + tid;
        const int row = I >> 3, c8 = (I & 7) ^ (row & 7);
        bsrc[g] = Bt + (size_t)(n0 + row) * K + c8*8;
        boff[g] = I * 8;
    }
    int ard[4], brd[4];
    #pragma unroll
    for (int i = 0; i < 4; i++) {
        ard[i] = (wm*64 + i*16 + l16) * 64;
        brd[i] = (wn*64 + i*16 + l16) * 64;
    }

    const int NKT = K >> 6;
    f32x4 acc[4][4] = {};

    #pragma unroll
    for (int g = 0; g < 2; g++) GLOAD_LDS16(asrc[g], &LDS[aoff[g]]);
    #pragma unroll
    for (int g = 0; g < 4; g++) GLOAD_LDS16(bsrc[g], &LDS[8192 + boff[g]]);
    #pragma unroll
    for (int g = 0; g < 2; g++) GLOAD_LDS16(asrc[g] + 64, &LDS[24576 + aoff[g]]);
    #pragma unroll
    for (int g = 0; g < 4; g++) GLOAD_LDS16(bsrc[g] + 64, &LDS[24576 + 8192 + boff[g]]);
    asm volatile("s_waitcnt vmcnt(6)" ::: "memory");
    __builtin_amdgcn_s_barrier();

    for (int t = 0; t < NKT; ++t) {
        const int cur = t % 3;
        const int ab  = cur * 24576;
        const int bb  = ab + 8192;
        const bool do_stage = (t + 2 < NKT);
        const int sb  = ((t + 2) % 3) * 24576;
        const int skt = (t + 2) << 6;

        short8 af[4], bfr[4];

        #pragma unroll
        for (int i = 0; i < 4; i++)
            af[i]  = *(const short8*)&LDS[ab + ard[i] + (quad ^ sw) * 8];
        #pragma unroll
        for (int j = 0; j < 4; j++)
            bfr[j] = *(const short8*)&LDS[bb + brd[j] + (quad ^ sw) * 8];
        if (do_stage) {
            GLOAD_LDS16(asrc[0] + skt, &LDS[sb + aoff[0]]);
            GLOAD_LDS16(asrc[1] + skt, &LDS[sb + aoff[1]]);
            GLOAD_LDS16(bsrc[0] + skt, &LDS[sb + 8192 + boff[0]]);
        }
        __builtin_amdgcn_s_barrier();
        asm volatile("s_waitcnt lgkmcnt(0)" ::: "memory");
        __builtin_amdgcn_sched_barrier(0);
        __builtin_amdgcn_s_setprio(1);
        #pragma unroll
        for (int i = 0; i < 4; i++)
            #pragma unroll
            for (int j = 0; j < 4; j++)
                acc[i][j] = __builtin_amdgcn_mfma_f32_16x16x32_bf16(af[i], bfr[j], acc[i][j], 0, 0, 0);
        __builtin_amdgcn_s_setprio(0);
        __builtin_amdgcn_s_barrier();

        #pragma unroll
        for (int i = 0; i < 4; i++)
            af[i]  = *(const short8*)&LDS[ab + ard[i] + ((quad + 4) ^ sw) * 8];
        #pragma unroll
        for (int j = 0; j < 4; j++)
            bfr[j] = *(const short8*)&LDS[bb + brd[j] + ((quad + 4) ^ sw) * 8];
        if (do_stage) {
            GLOAD_LDS16(bsrc[1] + skt, &LDS[sb + 8192 + boff[1]]);
            GLOAD_LDS16(bsrc[2] + skt, &LDS[sb + 8192 + boff[2]]);
            GLOAD_LDS16(bsrc[3] + skt, &LDS[sb + 8192 + boff[3]]);
        }
        __builtin_amdgcn_s_barrier();
        asm volatile("s_waitcnt lgkmcnt(0)" ::: "memory");
        __builtin_amdgcn_sched_barrier(0);
        __builtin_amdgcn_s_setprio(1);
        #pragma unroll
        for (int i = 0; i < 4; i++)
            #pragma unroll
            for (int j = 0; j < 4; j++)
                acc[i][j] = __builtin_amdgcn_mfma_f32_16x16x32_bf16(af[i], bfr[j], acc[i][j], 0, 0, 0);
        __builtin_amdgcn_s_setprio(0);
        if (do_stage)          asm volatile("s_waitcnt vmcnt(6)" ::: "memory");
        else if (t + 1 < NKT)  asm volatile("s_waitcnt vmcnt(0)" ::: "memory");
        __builtin_amdgcn_s_barrier();

        if (GATED && ((t & 15) == 15)) {
            const int seg = t >> 4;
            #pragma unroll
            for (int i = 0; i < 4; i++) {
                float gv[4];
                #pragma unroll
                for (int rg = 0; rg < 4; rg++) {
                    const int rrow = m0 + wm*64 + i*16 + quad*4 + rg;
                    gv[rg] = g9[(size_t)rrow * 9 + p*3 + seg];
                }
                #pragma unroll
                for (int j = 0; j < 4; j++)
                    #pragma unroll
                    for (int rg = 0; rg < 4; rg++)
                        acc[i][j][rg] *= gv[rg];
            }
        }
    }

    #pragma unroll
    for (int i = 0; i < 4; i++) {
        #pragma unroll
        for (int j = 0; j < 4; j++) {
            const int rrow = m0 + wm*64 + i*16 + quad*4;
            const int col  = n0 + wn*64 + j*16 + l16;
            #pragma unroll
            for (int rg = 0; rg < 4; rg++)
                st_c(&C[(size_t)(rrow + rg) * ldc + col], acc[i][j][rg]);
        }
    }
}

// ---------------- attention: one block per (b,t), all 16 heads ----------------
__global__ __launch_bounds__(256) void attn_kernel(const ushort* __restrict__ QKV,
                                                   ushort* __restrict__ AO) {
    const int tid = threadIdx.x;
    const int bt  = blockIdx.x;              // b*T_ + t
    const int t   = bt & (T_-1);
    const size_t qrow = (size_t)bt * K3_;
    const int e0 = tid * 4;

    const ushort4 q4 = *(const ushort4*)(QKV + qrow + e0);
    const float qf0 = bf2f(q4.x), qf1 = bf2f(q4.y), qf2 = bf2f(q4.z), qf3 = bf2f(q4.w);

    float sc[14];
    #pragma unroll
    for (int a = 0; a < 14; a++) {
        const int off = (a <= 3) ? a : (1 << (a - 2));
        float p = -1e30f;
        if (off <= t) {                      // block-uniform
            const ushort4 k4 = *(const ushort4*)(QKV + qrow - (size_t)off*K3_ + D_ + e0);
            float pp = qf0*bf2f(k4.x) + qf1*bf2f(k4.y) + qf2*bf2f(k4.z) + qf3*bf2f(k4.w);
            pp += __shfl_xor(pp, 1, 64);
            pp += __shfl_xor(pp, 2, 64);
            pp += __shfl_xor(pp, 4, 64);
            pp += __shfl_xor(pp, 8, 64);
            p = pp * 0.125f;                 // DH^-0.5
        }
        sc[a] = p;
    }
    float mx = -1e30f;
    #pragma unroll
    for (int a = 0; a < 14; a++) mx = fmaxf(mx, sc[a]);
    float ev[14], s = 0.0f;
    #pragma unroll
    for (int a = 0; a < 14; a++) { ev[a] = (sc[a] > -1e29f) ? expf(sc[a] - mx) : 0.0f; s += ev[a]; }
    const float rs = 1.0f / s;

    float a0 = 0.f, a1 = 0.f, a2 = 0.f, a3 = 0.f;
    #pragma unroll
    for (int a = 0; a < 14; a++) {
        const int off = (a <= 3) ? a : (1 << (a - 2));
        if (off <= t) {
            const ushort4 v4 = *(const ushort4*)(QKV + qrow - (size_t)off*K3_ + 2*D_ + e0);
            const float w = ev[a] * rs;
            a0 += w * bf2f(v4.x); a1 += w * bf2f(v4.y);
            a2 += w * bf2f(v4.z); a3 += w * bf2f(v4.w);
        }
    }
    ushort* dst = AO + (size_t)bt * D_ + e0;
    dst[0] = f2bf(a0); dst[1] = f2bf(a1); dst[2] = f2bf(a2); dst[3] = f2bf(a3);
}

extern "C" void kernel_launch(void* const* d_in, const int* in_sizes, int n_in,
                              void* d_out, int out_size, void* d_ws, size_t ws_size,
                              hipStream_t stream) {
    (void)in_sizes; (void)n_in; (void)out_size; (void)ws_size;
    const void* x    = d_in[0];
    const void* Wg_q = d_in[4];  const void* bg_q = d_in[5];
    const void* Wg_k = d_in[9];  const void* bg_k = d_in[10];
    const void* Wg_v = d_in[14]; const void* bg_v = d_in[15];

    char* ws = (char*)d_ws;
    int*    flag = (int*)ws;    ws += 16;
    float*  g9   = (float*)ws;  ws += (size_t)M_*9*4;            //   0.3 MB
    float*  part = (float*)ws;  ws += (size_t)B_*NCH_*D_*4;      //   0.26 MB
    ushort* Wt   = (ushort*)ws; ws += (size_t)K3_*K3_*2;         //  18 MB
    ushort* WoT  = (ushort*)ws; ws += (size_t)D_*D_*2;           //   2 MB
    ushort* Xc   = (ushort*)ws; ws += (size_t)M_*K3_*2;          //  50 MB (unscaled concat)
    ushort* QKV  = (ushort*)ws; ws += (size_t)M_*K3_*2;         //  50 MB
    ushort* AO   = (ushort*)ws; ws += (size_t)M_*D_*2;           //  17 MB  (total ~140 MB)

    detect_kernel<<<1, 256, 0, stream>>>((const ushort*)x, flag);
    gates_kernel<<<M_/4, 256, 0, stream>>>(x, Wg_q, bg_q, Wg_k, bg_k, Wg_v, bg_v, flag, g9);
    chunk_sum_kernel<<<dim3(D_/256, NCH_, B_), 256, 0, stream>>>(x, flag, part);
    scan_part_kernel<<<(B_*D_)/256, 256, 0, stream>>>(part);
    WPtrs wp;
    wp.w[0] = d_in[1];  wp.w[1] = d_in[2];  wp.w[2] = d_in[3];
    wp.w[3] = d_in[6];  wp.w[4] = d_in[7];  wp.w[5] = d_in[8];
    wp.w[6] = d_in[11]; wp.w[7] = d_in[12]; wp.w[8] = d_in[13];
    wp.w[9] = d_in[16];
    transpose_w_kernel<<<dim3(32, 32, 10), 256, 0, stream>>>(wp, flag, Wt, WoT);
    build_xs_kernel<<<dim3(D_/512, NCH_, B_), 256, 0, stream>>>(x, part, flag, Xc);
    // QKV: gated GEMM, M=8192, N=3072, K=3072 in 3 segments of 32 BK-tiles
    // grid = 32 mtiles x 8 ntiles = 256 blocks = exactly one device-wave
    gemm_qkv_kernel<<<256, 512, 0, stream>>>(Xc, Wt, QKV, g9);
    attn_kernel<<<B_*T_, 256, 0, stream>>>(QKV, AO);
    // out = AO @ Wo : M=8192, N=1024, K=1024  (f32 out, ungated), 256 blocks = 1 wave
    gemm_bt8_kernel<float, 4, false><<<256, 512, 0, stream>>>(AO, WoT, (float*)d_out, nullptr, D_, D_, D_);
}

// Round 3
// 509.901 us; speedup vs baseline: 1.1105x; 1.1105x over previous
//
#include <hip/hip_runtime.h>
#include <hip/hip_bf16.h>
#include <cstdint>

#define B_   2
#define T_   4096
#define D_   1024
#define H_   16
#define DH_  64
#define M_   (B_*T_)     // 8192 rows
#define K3_  (3*D_)      // 3072
#define TC_  128         // cumsum chunk
#define NCH_ (T_/TC_)    // 32 chunks

typedef __attribute__((ext_vector_type(4))) float  f32x4;
typedef __attribute__((ext_vector_type(8))) short  short8;

__device__ __forceinline__ float bf2f(ushort u) {
    union { uint32_t i; float f; } v; v.i = ((uint32_t)u) << 16; return v.f;
}
__device__ __forceinline__ ushort f2bf(float f) {
    union { float f; uint32_t i; } v; v.f = f;
    uint32_t r = v.i + 0x7FFF + ((v.i >> 16) & 1);
    return (ushort)(r >> 16);
}

template<bool F32>
__device__ __forceinline__ float ld_in(const void* p, size_t i) {
    if (F32) return ((const float*)p)[i];
    return bf2f(((const ushort*)p)[i]);
}

// store helpers: bf16 internal buffers vs f32 final output
__device__ __forceinline__ void st_c(ushort* p, float v) { *p = f2bf(v); }
__device__ __forceinline__ void st_c(float*  p, float v) { *p = v; }

#define GLOAD_LDS16(g, l) \
    __builtin_amdgcn_global_load_lds((const __attribute__((address_space(1))) void*)(g), \
                                     (__attribute__((address_space(3))) void*)(l), 16, 0, 0)

// ---------------- P0: dtype detector ----------------
__global__ void detect_kernel(const ushort* __restrict__ xu, int* __restrict__ flag) {
    __shared__ int cnt;
    if (threadIdx.x == 0) cnt = 0;
    __syncthreads();
    int c = 0;
    for (int i = threadIdx.x; i < 16384; i += 256) {
        ushort u = xu[i];
        if ((u & 0x7F80) == 0x7F80) c++;
    }
    if (c) atomicAdd(&cnt, c);
    __syncthreads();
    if (threadIdx.x == 0) flag[0] = (cnt > 0) ? 1 : 0;
}

// ---------------- P1: gates -> telescoping chain ratios ----------------
// g9[row][p*3+s] stores: s=0: g0/g1', s=1: g1'/g2', s=2: g2'  (g'=max(g,1e-30))
template<bool F32>
__device__ __forceinline__ void gates_body(const void* x,
                                           const void* Wg_q, const void* bg_q,
                                           const void* Wg_k, const void* bg_k,
                                           const void* Wg_v, const void* bg_v,
                                           float* __restrict__ g9) {
    const int wave = threadIdx.x >> 6, lane = threadIdx.x & 63;
    const int row  = blockIdx.x * 4 + wave;
    const size_t xoff = (size_t)row * D_;
    float acc[9] = {0,0,0,0,0,0,0,0,0};
    for (int d = lane; d < D_; d += 64) {
        float xv = ld_in<F32>(x, xoff + d);
        #pragma unroll
        for (int c = 0; c < 3; c++) {
            acc[0+c] += xv * ld_in<F32>(Wg_q, d*3+c);
            acc[3+c] += xv * ld_in<F32>(Wg_k, d*3+c);
            acc[6+c] += xv * ld_in<F32>(Wg_v, d*3+c);
        }
    }
    #pragma unroll
    for (int i = 0; i < 9; i++) {
        #pragma unroll
        for (int o = 32; o >= 1; o >>= 1) acc[i] += __shfl_xor(acc[i], o, 64);
    }
    const void* bgs[3] = {bg_q, bg_k, bg_v};
    float g[9];
    #pragma unroll
    for (int p = 0; p < 3; p++) {
        float l0 = acc[p*3+0] + ld_in<F32>(bgs[p], 0);
        float l1 = acc[p*3+1] + ld_in<F32>(bgs[p], 1);
        float l2 = acc[p*3+2] + ld_in<F32>(bgs[p], 2);
        float mx = fmaxf(l0, fmaxf(l1, l2));
        float e0 = expf(l0-mx), e1 = expf(l1-mx), e2 = expf(l2-mx);
        float s  = e0+e1+e2;
        float g0 = fminf(e0/s, 0.6f), g1 = fminf(e1/s, 0.6f), g2 = fminf(e2/s, 0.6f);
        float s2 = g0+g1+g2;
        g0 /= s2; g1 /= s2; g2 /= s2;
        float g1c = fmaxf(g1, 1e-30f), g2c = fmaxf(g2, 1e-30f);
        g[p*3+0] = g0 / g1c;
        g[p*3+1] = g1c / g2c;
        g[p*3+2] = g2c;
    }
    if (lane == 0) {
        #pragma unroll
        for (int i = 0; i < 9; i++) g9[(size_t)row*9 + i] = g[i];
    }
}
__global__ void gates_kernel(const void* x,
                             const void* Wg_q, const void* bg_q,
                             const void* Wg_k, const void* bg_k,
                             const void* Wg_v, const void* bg_v,
                             const int* __restrict__ flag, float* __restrict__ g9) {
    if (flag[0]) gates_body<true >(x, Wg_q, bg_q, Wg_k, bg_k, Wg_v, bg_v, g9);
    else         gates_body<false>(x, Wg_q, bg_q, Wg_k, bg_k, Wg_v, bg_v, g9);
}

// ---------------- P2: per-chunk sums ----------------
template<bool F32>
__device__ __forceinline__ void chunk_sum_body(const void* x, float* __restrict__ part) {
    const int d = blockIdx.x * 256 + threadIdx.x;
    const int tc = blockIdx.y, b = blockIdx.z;
    const size_t base = ((size_t)b*T_ + (size_t)tc*TC_) * D_ + d;
    float s = 0.f;
    for (int i = 0; i < TC_; i++) s += ld_in<F32>(x, base + (size_t)i * D_);
    part[((size_t)b*NCH_ + tc) * D_ + d] = s;
}
__global__ void chunk_sum_kernel(const void* x, const int* __restrict__ flag,
                                 float* __restrict__ part) {
    if (flag[0]) chunk_sum_body<true >(x, part);
    else         chunk_sum_body<false>(x, part);
}

// ---------------- P3: exclusive scan of chunk sums ----------------
__global__ void scan_part_kernel(float* __restrict__ part) {
    const int idx = blockIdx.x * 256 + threadIdx.x;   // 0..2047
    const int b = idx >> 10, d = idx & (D_-1);
    float run = 0.f;
    for (int tc = 0; tc < NCH_; tc++) {
        size_t o = ((size_t)b*NCH_ + tc) * D_ + d;
        float v = part[o]; part[o] = run; run += v;
    }
}

// ---------------- P4: build UNSCALED concat input Xc[row] = [x | integ | deriv] ----------------
template<bool F32>
__device__ __forceinline__ void build_xs_body(const void* x, const float* __restrict__ part,
                                              ushort* __restrict__ Xc) {
    const int d0 = (blockIdx.x * 256 + threadIdx.x) * 2;
    const int tc = blockIdx.y, b = blockIdx.z;
    const int t0 = tc * TC_;
    float carry0 = part[((size_t)b*NCH_ + tc) * D_ + d0];
    float carry1 = part[((size_t)b*NCH_ + tc) * D_ + d0 + 1];
    const size_t xbase = ((size_t)b*T_ + t0) * D_ + d0;
    float prev0 = (t0 > 0) ? ld_in<F32>(x, xbase - D_)     : 0.0f;
    float prev1 = (t0 > 0) ? ld_in<F32>(x, xbase - D_ + 1) : 0.0f;
    for (int i = 0; i < TC_; i++) {
        const int t = t0 + i;
        float xv0 = ld_in<F32>(x, xbase + (size_t)i * D_);
        float xv1 = ld_in<F32>(x, xbase + (size_t)i * D_ + 1);
        carry0 += xv0; carry1 += xv1;
        const float rinv = 1.0f / (float)(t + 1);
        float in0 = carry0 * rinv, in1 = carry1 * rinv;
        float de0 = (t == 0) ? 0.0f : (xv0 - prev0);
        float de1 = (t == 0) ? 0.0f : (xv1 - prev1);
        prev0 = xv0; prev1 = xv1;
        const size_t base = ((size_t)b*T_ + t) * K3_ + d0;
        *(ushort2*)(Xc + base       ) = make_ushort2(f2bf(xv0), f2bf(xv1));
        *(ushort2*)(Xc + base +   D_) = make_ushort2(f2bf(in0), f2bf(in1));
        *(ushort2*)(Xc + base + 2*D_) = make_ushort2(f2bf(de0), f2bf(de1));
    }
}
__global__ void build_xs_kernel(const void* x, const float* __restrict__ part,
                                const int* __restrict__ flag, ushort* __restrict__ Xc) {
    if (flag[0]) build_xs_body<true >(x, part, Xc);
    else         build_xs_body<false>(x, part, Xc);
}

// ---------------- P5: weight transpose -> (N,K) bf16 ----------------
struct WPtrs { const void* w[10]; };
template<bool F32>
__device__ __forceinline__ void transpose_w_body(WPtrs ptrs, ushort* __restrict__ Wt,
                                                 ushort* __restrict__ WoT) {
    const int z = blockIdx.z;                 // 0..8: W{p,j}; 9: Wo
    const void* src = ptrs.w[z];
    __shared__ float tile[32][33];
    const int tx = threadIdx.x & 31, ty = threadIdx.x >> 5;
    const int d0 = blockIdx.x * 32, c0 = blockIdx.y * 32;
    #pragma unroll
    for (int i = 0; i < 4; i++) {
        int r = ty + i*8;
        tile[r][tx] = ld_in<F32>(src, (size_t)(d0 + r) * D_ + c0 + tx);
    }
    __syncthreads();
    if (z < 9) {
        const int p = z / 3, j = z % 3;
        #pragma unroll
        for (int i = 0; i < 4; i++) {
            int r = ty + i*8;
            Wt[(size_t)(p*D_ + c0 + r) * K3_ + j*D_ + d0 + tx] = f2bf(tile[tx][r]);
        }
    } else {
        #pragma unroll
        for (int i = 0; i < 4; i++) {
            int r = ty + i*8;
            WoT[(size_t)(c0 + r) * D_ + d0 + tx] = f2bf(tile[tx][r]);
        }
    }
}
__global__ void transpose_w_kernel(WPtrs ptrs, const int* __restrict__ flag,
                                   ushort* __restrict__ Wt, ushort* __restrict__ WoT) {
    if (flag[0]) transpose_w_body<true >(ptrs, Wt, WoT);
    else         transpose_w_body<false>(ptrs, Wt, WoT);
}

// ---------------- QKV GEMM v3: 256x384 tile, BK=32, ring-3 LDS ----------------
// C(8192x3072) = Xc * Wt^T, bf16 in/out, f32 acc, gated.
// 8 waves (2M x 4N) -> per-wave 128x96 (8x6 frags, acc=192 regs).
// Per-CU per K-tile: LDS reads 112 KiB (~1349 cyc @85B/cyc) < MFMA 384x4.85
// (~1863 cyc) => compute-bound (r1's 128x256 was LDS-read-bound: 1542>1242).
//
// LDS swizzle (fixes r2's 8-way conflict, 1.1e7 -> ~0):
//   read octet   gq = quad ^ ((l16>>1)&3)
//   stage source octet = (I&3) ^ ((row>>1)&3), linear LDS dest (same involution
//   both sides, rule 21). 16 lanes/quad-group -> 8 bank positions x2 = 2-way (free).
//
// Register diet (fixes r2's spill: WRITE 121MB -> ~50MB):
//   2 staging base ptrs (A,B) + constant row strides (128*K3_ apart),
//   4 MFMA phases x 12 MFMA, af[2] per phase, bfr[6] persistent.
//   Live ~ acc192 + bfr24 + af8 + ptrs4 + temps ~ 235 < 256.
//
// vmcnt ledger (5 loads/tile/thread: A x2, B x3, issued across phases in order):
//   end of tile t: newest 5 outstanding = tile (t+2)'s -> vmcnt(5) proves (t+1)
//   landed. Drain vmcnt(0) only at t == NKT-2.
__global__ __launch_bounds__(512, 2) void gemm_qkv_kernel(
        const ushort* __restrict__ Abase,
        const ushort* __restrict__ Bt,
        ushort* __restrict__ C,
        const float* __restrict__ g9) {
    constexpr int BUFE = 20480;          // ushorts per ring buffer (40 KB)
    constexpr int NKT  = K3_ / 32;       // 96
    constexpr int RSTR = 128 * K3_;      // 128-row stride in ushorts (A/B granule groups)
    __shared__ __align__(16) ushort LDS[3 * BUFE];   // 122880 B
    const int tid  = threadIdx.x;
    const int lane = tid & 63;
    const int wave = tid >> 6;
    const int wm   = wave >> 2;          // 0..1
    const int wn   = wave & 3;           // 0..3
    const int quad = lane >> 4, l16 = lane & 15;
    const int gq   = quad ^ ((l16 >> 1) & 3);        // swizzled read octet

    // XCD-chunked bijective swizzle: 256 blocks, cpx=32, mchunk=4
    const int wg  = (blockIdx.x % 8) * 32 + blockIdx.x / 8;
    const int rem = wg & 31;
    const int mt  = (wg >> 5) * 4 + (rem & 3);
    const int nt  = rem >> 2;
    const int m0  = mt * 256;
    const int n0  = nt * 384;

    // staging: thread owns LDS granules {tid, tid+512} of A, {tid, tid+512, tid+1024} of B
    // (row advances by 128 per +512 granules; (row>>1)&3 invariant under +128)
    const int arow = tid >> 2;
    const int acg  = (tid & 3) ^ ((arow >> 1) & 3);  // swizzled source octet
    const ushort* pA = Abase + (size_t)(m0 + arow) * K3_ + acg * 8;
    const ushort* pB = Bt    + (size_t)(n0 + arow) * K3_ + acg * 8;
    const int l8 = tid * 8;

    f32x4 acc[8][6] = {};

    // ---- prologue: tile0 -> buf0, tile1 -> buf1 ----
    GLOAD_LDS16(pA,               &LDS[l8]);
    GLOAD_LDS16(pA + RSTR,        &LDS[l8 + 4096]);
    GLOAD_LDS16(pB,               &LDS[8192 + l8]);
    GLOAD_LDS16(pB + RSTR,        &LDS[8192 + l8 + 4096]);
    GLOAD_LDS16(pB + 2*RSTR,      &LDS[8192 + l8 + 8192]);
    GLOAD_LDS16(pA + 32,          &LDS[BUFE + l8]);
    GLOAD_LDS16(pA + RSTR + 32,   &LDS[BUFE + l8 + 4096]);
    GLOAD_LDS16(pB + 32,          &LDS[BUFE + 8192 + l8]);
    GLOAD_LDS16(pB + RSTR + 32,   &LDS[BUFE + 8192 + l8 + 4096]);
    GLOAD_LDS16(pB + 2*RSTR + 32, &LDS[BUFE + 8192 + l8 + 8192]);
    pA += 64; pB += 64;                               // now point at tile 2
    asm volatile("s_waitcnt vmcnt(5)" ::: "memory");
    __builtin_amdgcn_s_barrier();

    for (int t = 0; t < NKT; ++t) {
        const int bs = (t % 3) * BUFE;
        const bool do_stage = (t + 2 < NKT);
        const int sb = ((t + 2) % 3) * BUFE;
        const int abase = bs + (wm*128 + l16)*32 + gq*8;          // + i*512
        const int bbase = bs + 8192 + (wn*96 + l16)*32 + gq*8;    // + j*512

        short8 bfr[6], af[2];

        // ---- P0: bfr[0..5], af rows 0-1 ----
        #pragma unroll
        for (int j = 0; j < 6; j++) bfr[j] = *(const short8*)&LDS[bbase + j*512];
        af[0] = *(const short8*)&LDS[abase];
        af[1] = *(const short8*)&LDS[abase + 512];
        if (do_stage) {
            GLOAD_LDS16(pA,        &LDS[sb + l8]);
            GLOAD_LDS16(pA + RSTR, &LDS[sb + l8 + 4096]);
        }
        __builtin_amdgcn_s_barrier();
        asm volatile("s_waitcnt lgkmcnt(0)" ::: "memory");
        __builtin_amdgcn_sched_barrier(0);
        __builtin_amdgcn_s_setprio(1);
        #pragma unroll
        for (int ii = 0; ii < 2; ii++)
            #pragma unroll
            for (int j = 0; j < 6; j++)
                acc[ii][j] = __builtin_amdgcn_mfma_f32_16x16x32_bf16(af[ii], bfr[j], acc[ii][j], 0, 0, 0);
        __builtin_amdgcn_s_setprio(0);
        __builtin_amdgcn_s_barrier();

        // ---- P1: af rows 2-3 ----
        af[0] = *(const short8*)&LDS[abase + 2*512];
        af[1] = *(const short8*)&LDS[abase + 3*512];
        if (do_stage) GLOAD_LDS16(pB, &LDS[sb + 8192 + l8]);
        __builtin_amdgcn_s_barrier();
        asm volatile("s_waitcnt lgkmcnt(0)" ::: "memory");
        __builtin_amdgcn_sched_barrier(0);
        __builtin_amdgcn_s_setprio(1);
        #pragma unroll
        for (int ii = 0; ii < 2; ii++)
            #pragma unroll
            for (int j = 0; j < 6; j++)
                acc[2+ii][j] = __builtin_amdgcn_mfma_f32_16x16x32_bf16(af[ii], bfr[j], acc[2+ii][j], 0, 0, 0);
        __builtin_amdgcn_s_setprio(0);
        __builtin_amdgcn_s_barrier();

        // ---- P2: af rows 4-5 ----
        af[0] = *(const short8*)&LDS[abase + 4*512];
        af[1] = *(const short8*)&LDS[abase + 5*512];
        if (do_stage) GLOAD_LDS16(pB + RSTR, &LDS[sb + 8192 + l8 + 4096]);
        __builtin_amdgcn_s_barrier();
        asm volatile("s_waitcnt lgkmcnt(0)" ::: "memory");
        __builtin_amdgcn_sched_barrier(0);
        __builtin_amdgcn_s_setprio(1);
        #pragma unroll
        for (int ii = 0; ii < 2; ii++)
            #pragma unroll
            for (int j = 0; j < 6; j++)
                acc[4+ii][j] = __builtin_amdgcn_mfma_f32_16x16x32_bf16(af[ii], bfr[j], acc[4+ii][j], 0, 0, 0);
        __builtin_amdgcn_s_setprio(0);
        __builtin_amdgcn_s_barrier();

        // ---- P3: af rows 6-7 + tile-boundary counted drain ----
        af[0] = *(const short8*)&LDS[abase + 6*512];
        af[1] = *(const short8*)&LDS[abase + 7*512];
        if (do_stage) GLOAD_LDS16(pB + 2*RSTR, &LDS[sb + 8192 + l8 + 8192]);
        __builtin_amdgcn_s_barrier();
        asm volatile("s_waitcnt lgkmcnt(0)" ::: "memory");
        __builtin_amdgcn_sched_barrier(0);
        __builtin_amdgcn_s_setprio(1);
        #pragma unroll
        for (int ii = 0; ii < 2; ii++)
            #pragma unroll
            for (int j = 0; j < 6; j++)
                acc[6+ii][j] = __builtin_amdgcn_mfma_f32_16x16x32_bf16(af[ii], bfr[j], acc[6+ii][j], 0, 0, 0);
        __builtin_amdgcn_s_setprio(0);
        if (do_stage)          asm volatile("s_waitcnt vmcnt(5)" ::: "memory");
        else if (t + 1 < NKT)  asm volatile("s_waitcnt vmcnt(0)" ::: "memory");
        __builtin_amdgcn_s_barrier();

        pA += 32; pB += 32;

        if ((t & 31) == 31) {
            // telescoping gate fold; p per 16-col fragment (never straddles 1024)
            const int seg = t >> 5;
            int pj3[6];
            #pragma unroll
            for (int j = 0; j < 6; j++) pj3[j] = ((n0 + wn*96 + j*16) >> 10) * 3;
            #pragma unroll
            for (int i = 0; i < 8; i++) {
                #pragma unroll
                for (int rg = 0; rg < 4; rg++) {
                    const int rrow = m0 + wm*128 + i*16 + quad*4 + rg;
                    const float* gr = &g9[(size_t)rrow * 9 + seg];
                    #pragma unroll
                    for (int j = 0; j < 6; j++)
                        acc[i][j][rg] *= gr[pj3[j]];
                }
            }
        }
    }

    // epilogue: C/D layout col=lane&15, row=quad*4+reg  [m89/m91 verified]
    #pragma unroll
    for (int i = 0; i < 8; i++) {
        #pragma unroll
        for (int j = 0; j < 6; j++) {
            const int rrow = m0 + wm*128 + i*16 + quad*4;
            const int col  = n0 + wn*96 + j*16 + l16;
            #pragma unroll
            for (int rg = 0; rg < 4; rg++)
                C[(size_t)(rrow + rg) * K3_ + col] = f2bf(acc[i][j][rg]);
        }
    }
}

// ---------------- out-proj GEMM (round-1 kernel, proven): 128x256 tile ------
template<typename CT, int NTILES, bool GATED>
__global__ __launch_bounds__(512, 2) void gemm_bt8_kernel(
        const ushort* __restrict__ Abase,
        const ushort* __restrict__ Bt,
        CT* __restrict__ C,
        const float* __restrict__ g9,
        int K, int lda, int ldc) {
    __shared__ __align__(16) ushort LDS[3 * 24576];
    const int tid  = threadIdx.x;
    const int lane = tid & 63;
    const int wave = tid >> 6;
    const int wm   = wave >> 2;
    const int wn   = wave & 3;
    const int quad = lane >> 4, l16 = lane & 15, sw = l16 & 7;

    const int MT     = M_ / 128;                 // 64
    const int cpx    = (MT * NTILES) / 8;
    const int wg     = (blockIdx.x % 8) * cpx + blockIdx.x / 8;
    const int mchunk = MT / 8;                   // 8
    const int rem    = wg % (mchunk * NTILES);
    const int mt     = (wg / (mchunk * NTILES)) * mchunk + (rem % mchunk);
    const int nt     = rem / mchunk;
    const int m0 = mt * 128;
    const int n0 = nt * 256;
    const int p  = n0 >> 10;

    const ushort* asrc[2]; int aoff[2];
    #pragma unroll
    for (int g = 0; g < 2; g++) {
        const int I = g*512 + tid;
        const int row = I >> 3, c8 = (I & 7) ^ (row & 7);
        asrc[g] = Abase + (size_t)(m0 + row) * lda + c8*8;
        aoff[g] = I * 8;
    }
    const ushort* bsrc[4]; int boff[4];
    #pragma unroll
    for (int g = 0; g < 4; g++) {
        const int I = g*512 + tid;
        const int row = I >> 3, c8 = (I & 7) ^ (row & 7);
        bsrc[g] = Bt + (size_t)(n0 + row) * K + c8*8;
        boff[g] = I * 8;
    }
    int ard[4], brd[4];
    #pragma unroll
    for (int i = 0; i < 4; i++) {
        ard[i] = (wm*64 + i*16 + l16) * 64;
        brd[i] = (wn*64 + i*16 + l16) * 64;
    }

    const int NKT = K >> 6;
    f32x4 acc[4][4] = {};

    #pragma unroll
    for (int g = 0; g < 2; g++) GLOAD_LDS16(asrc[g], &LDS[aoff[g]]);
    #pragma unroll
    for (int g = 0; g < 4; g++) GLOAD_LDS16(bsrc[g], &LDS[8192 + boff[g]]);
    #pragma unroll
    for (int g = 0; g < 2; g++) GLOAD_LDS16(asrc[g] + 64, &LDS[24576 + aoff[g]]);
    #pragma unroll
    for (int g = 0; g < 4; g++) GLOAD_LDS16(bsrc[g] + 64, &LDS[24576 + 8192 + boff[g]]);
    asm volatile("s_waitcnt vmcnt(6)" ::: "memory");
    __builtin_amdgcn_s_barrier();

    for (int t = 0; t < NKT; ++t) {
        const int cur = t % 3;
        const int ab  = cur * 24576;
        const int bb  = ab + 8192;
        const bool do_stage = (t + 2 < NKT);
        const int sb  = ((t + 2) % 3) * 24576;
        const int skt = (t + 2) << 6;

        short8 af[4], bfr[4];

        #pragma unroll
        for (int i = 0; i < 4; i++)
            af[i]  = *(const short8*)&LDS[ab + ard[i] + (quad ^ sw) * 8];
        #pragma unroll
        for (int j = 0; j < 4; j++)
            bfr[j] = *(const short8*)&LDS[bb + brd[j] + (quad ^ sw) * 8];
        if (do_stage) {
            GLOAD_LDS16(asrc[0] + skt, &LDS[sb + aoff[0]]);
            GLOAD_LDS16(asrc[1] + skt, &LDS[sb + aoff[1]]);
            GLOAD_LDS16(bsrc[0] + skt, &LDS[sb + 8192 + boff[0]]);
        }
        __builtin_amdgcn_s_barrier();
        asm volatile("s_waitcnt lgkmcnt(0)" ::: "memory");
        __builtin_amdgcn_sched_barrier(0);
        __builtin_amdgcn_s_setprio(1);
        #pragma unroll
        for (int i = 0; i < 4; i++)
            #pragma unroll
            for (int j = 0; j < 4; j++)
                acc[i][j] = __builtin_amdgcn_mfma_f32_16x16x32_bf16(af[i], bfr[j], acc[i][j], 0, 0, 0);
        __builtin_amdgcn_s_setprio(0);
        __builtin_amdgcn_s_barrier();

        #pragma unroll
        for (int i = 0; i < 4; i++)
            af[i]  = *(const short8*)&LDS[ab + ard[i] + ((quad + 4) ^ sw) * 8];
        #pragma unroll
        for (int j = 0; j < 4; j++)
            bfr[j] = *(const short8*)&LDS[bb + brd[j] + ((quad + 4) ^ sw) * 8];
        if (do_stage) {
            GLOAD_LDS16(bsrc[1] + skt, &LDS[sb + 8192 + boff[1]]);
            GLOAD_LDS16(bsrc[2] + skt, &LDS[sb + 8192 + boff[2]]);
            GLOAD_LDS16(bsrc[3] + skt, &LDS[sb + 8192 + boff[3]]);
        }
        __builtin_amdgcn_s_barrier();
        asm volatile("s_waitcnt lgkmcnt(0)" ::: "memory");
        __builtin_amdgcn_sched_barrier(0);
        __builtin_amdgcn_s_setprio(1);
        #pragma unroll
        for (int i = 0; i < 4; i++)
            #pragma unroll
            for (int j = 0; j < 4; j++)
                acc[i][j] = __builtin_amdgcn_mfma_f32_16x16x32_bf16(af[i], bfr[j], acc[i][j], 0, 0, 0);
        __builtin_amdgcn_s_setprio(0);
        if (do_stage)          asm volatile("s_waitcnt vmcnt(6)" ::: "memory");
        else if (t + 1 < NKT)  asm volatile("s_waitcnt vmcnt(0)" ::: "memory");
        __builtin_amdgcn_s_barrier();

        if (GATED && ((t & 15) == 15)) {
            const int seg = t >> 4;
            #pragma unroll
            for (int i = 0; i < 4; i++) {
                float gv[4];
                #pragma unroll
                for (int rg = 0; rg < 4; rg++) {
                    const int rrow = m0 + wm*64 + i*16 + quad*4 + rg;
                    gv[rg] = g9[(size_t)rrow * 9 + p*3 + seg];
                }
                #pragma unroll
                for (int j = 0; j < 4; j++)
                    #pragma unroll
                    for (int rg = 0; rg < 4; rg++)
                        acc[i][j][rg] *= gv[rg];
            }
        }
    }

    #pragma unroll
    for (int i = 0; i < 4; i++) {
        #pragma unroll
        for (int j = 0; j < 4; j++) {
            const int rrow = m0 + wm*64 + i*16 + quad*4;
            const int col  = n0 + wn*64 + j*16 + l16;
            #pragma unroll
            for (int rg = 0; rg < 4; rg++)
                st_c(&C[(size_t)(rrow + rg) * ldc + col], acc[i][j][rg]);
        }
    }
}

// ---------------- attention: one block per (b,t), all 16 heads ----------------
__global__ __launch_bounds__(256) void attn_kernel(const ushort* __restrict__ QKV,
                                                   ushort* __restrict__ AO) {
    const int tid = threadIdx.x;
    const int bt  = blockIdx.x;              // b*T_ + t
    const int t   = bt & (T_-1);
    const size_t qrow = (size_t)bt * K3_;
    const int e0 = tid * 4;

    const ushort4 q4 = *(const ushort4*)(QKV + qrow + e0);
    const float qf0 = bf2f(q4.x), qf1 = bf2f(q4.y), qf2 = bf2f(q4.z), qf3 = bf2f(q4.w);

    float sc[14];
    #pragma unroll
    for (int a = 0; a < 14; a++) {
        const int off = (a <= 3) ? a : (1 << (a - 2));
        float p = -1e30f;
        if (off <= t) {                      // block-uniform
            const ushort4 k4 = *(const ushort4*)(QKV + qrow - (size_t)off*K3_ + D_ + e0);
            float pp = qf0*bf2f(k4.x) + qf1*bf2f(k4.y) + qf2*bf2f(k4.z) + qf3*bf2f(k4.w);
            pp += __shfl_xor(pp, 1, 64);
            pp += __shfl_xor(pp, 2, 64);
            pp += __shfl_xor(pp, 4, 64);
            pp += __shfl_xor(pp, 8, 64);
            p = pp * 0.125f;                 // DH^-0.5
        }
        sc[a] = p;
    }
    float mx = -1e30f;
    #pragma unroll
    for (int a = 0; a < 14; a++) mx = fmaxf(mx, sc[a]);
    float ev[14], s = 0.0f;
    #pragma unroll
    for (int a = 0; a < 14; a++) { ev[a] = (sc[a] > -1e29f) ? expf(sc[a] - mx) : 0.0f; s += ev[a]; }
    const float rs = 1.0f / s;

    float a0 = 0.f, a1 = 0.f, a2 = 0.f, a3 = 0.f;
    #pragma unroll
    for (int a = 0; a < 14; a++) {
        const int off = (a <= 3) ? a : (1 << (a - 2));
        if (off <= t) {
            const ushort4 v4 = *(const ushort4*)(QKV + qrow - (size_t)off*K3_ + 2*D_ + e0);
            const float w = ev[a] * rs;
            a0 += w * bf2f(v4.x); a1 += w * bf2f(v4.y);
            a2 += w * bf2f(v4.z); a3 += w * bf2f(v4.w);
        }
    }
    ushort* dst = AO + (size_t)bt * D_ + e0;
    dst[0] = f2bf(a0); dst[1] = f2bf(a1); dst[2] = f2bf(a2); dst[3] = f2bf(a3);
}

extern "C" void kernel_launch(void* const* d_in, const int* in_sizes, int n_in,
                              void* d_out, int out_size, void* d_ws, size_t ws_size,
                              hipStream_t stream) {
    (void)in_sizes; (void)n_in; (void)out_size; (void)ws_size;
    const void* x    = d_in[0];
    const void* Wg_q = d_in[4];  const void* bg_q = d_in[5];
    const void* Wg_k = d_in[9];  const void* bg_k = d_in[10];
    const void* Wg_v = d_in[14]; const void* bg_v = d_in[15];

    char* ws = (char*)d_ws;
    int*    flag = (int*)ws;    ws += 16;
    float*  g9   = (float*)ws;  ws += (size_t)M_*9*4;            //   0.3 MB
    float*  part = (float*)ws;  ws += (size_t)B_*NCH_*D_*4;      //   0.26 MB
    ushort* Wt   = (ushort*)ws; ws += (size_t)K3_*K3_*2;         //  18 MB
    ushort* WoT  = (ushort*)ws; ws += (size_t)D_*D_*2;           //   2 MB
    ushort* Xc   = (ushort*)ws; ws += (size_t)M_*K3_*2;          //  50 MB (unscaled concat)
    ushort* QKV  = (ushort*)ws; ws += (size_t)M_*K3_*2;         //  50 MB
    ushort* AO   = (ushort*)ws; ws += (size_t)M_*D_*2;           //  17 MB  (total ~140 MB)

    detect_kernel<<<1, 256, 0, stream>>>((const ushort*)x, flag);
    gates_kernel<<<M_/4, 256, 0, stream>>>(x, Wg_q, bg_q, Wg_k, bg_k, Wg_v, bg_v, flag, g9);
    chunk_sum_kernel<<<dim3(D_/256, NCH_, B_), 256, 0, stream>>>(x, flag, part);
    scan_part_kernel<<<(B_*D_)/256, 256, 0, stream>>>(part);
    WPtrs wp;
    wp.w[0] = d_in[1];  wp.w[1] = d_in[2];  wp.w[2] = d_in[3];
    wp.w[3] = d_in[6];  wp.w[4] = d_in[7];  wp.w[5] = d_in[8];
    wp.w[6] = d_in[11]; wp.w[7] = d_in[12]; wp.w[8] = d_in[13];
    wp.w[9] = d_in[16];
    transpose_w_kernel<<<dim3(32, 32, 10), 256, 0, stream>>>(wp, flag, Wt, WoT);
    build_xs_kernel<<<dim3(D_/512, NCH_, B_), 256, 0, stream>>>(x, part, flag, Xc);
    // QKV: gated GEMM, M=8192, N=3072, K=3072 in 3 segments of 32 BK-tiles
    // grid = 32 mtiles x 8 ntiles = 256 blocks = exactly one device-wave
    gemm_qkv_kernel<<<256, 512, 0, stream>>>(Xc, Wt, QKV, g9);
    attn_kernel<<<B_*T_, 256, 0, stream>>>(QKV, AO);
    // out = AO @ Wo : M=8192, N=1024, K=1024  (f32 out, ungated), 256 blocks = 1 wave
    gemm_bt8_kernel<float, 4, false><<<256, 512, 0, stream>>>(AO, WoT, (float*)d_out, nullptr, D_, D_, D_);
}